// Round 8
// baseline (54.107 us; speedup 1.0000x reference)
//
#include <hip/hip_runtime.h>

typedef float    f32x4  __attribute__((ext_vector_type(4)));
typedef float    f32x16 __attribute__((ext_vector_type(16)));
typedef _Float16 half8  __attribute__((ext_vector_type(8)));

constexpr int NB = 8;
constexpr int NQ = 2048;
constexpr int NKEY = 2048;
constexpr int DD = 64;
constexpr int KB = 64;     // keys per iteration (two 32-key chunks)
constexpr int QBLK = 128;  // q rows per block (4 waves x 32)
constexpr int VSTR = 144;  // V^T LDS row stride (bytes), 16B-aligned

// scores kept in log2 domain: fold log2(e) into the 1/sqrt(d) scale
#define QSCALE (0.125f * 1.44269504088896340736f)

__device__ inline unsigned pkh(float a, float b) {
    return __builtin_bit_cast(unsigned, __builtin_amdgcn_cvt_pkrtz(a, b));
}

// P (f32 C-layout regs) -> f16 A-fragments, then PV from LDS V^T.
// Verified R5/R6: A0 = keys hi*8+{0..7}, A1 = keys 16+hi*8+{0..7};
// V^T LDS: byte (d)*VSTR + key*2.  koff = chunk byte offset (0 or 64).
__device__ __forceinline__ void pv_chunk(
    const f32x16& sv, const char* __restrict__ vsm, int koff,
    int hi, int ql, f32x16& o0, f32x16& o1)
{
    const unsigned w0 = pkh(sv[0],  sv[1]),  w1 = pkh(sv[2],  sv[3]);
    const unsigned w2 = pkh(sv[4],  sv[5]),  w3 = pkh(sv[6],  sv[7]);
    const unsigned w4 = pkh(sv[8],  sv[9]),  w5 = pkh(sv[10], sv[11]);
    const unsigned w6 = pkh(sv[12], sv[13]), w7 = pkh(sv[14], sv[15]);
    const unsigned p0 = __shfl_xor(w0, 32), p1 = __shfl_xor(w1, 32);
    const unsigned p2 = __shfl_xor(w2, 32), p3 = __shfl_xor(w3, 32);
    const unsigned p4 = __shfl_xor(w4, 32), p5 = __shfl_xor(w5, 32);
    const unsigned p6 = __shfl_xor(w6, 32), p7 = __shfl_xor(w7, 32);
    const bool h1 = (hi != 0);
    union { unsigned u[4]; half8 h; } A0, A1;
    A0.u[0] = h1 ? p2 : w0;  A0.u[1] = h1 ? p3 : w1;
    A0.u[2] = h1 ? w2 : p0;  A0.u[3] = h1 ? w3 : p1;
    A1.u[0] = h1 ? p6 : w4;  A1.u[1] = h1 ? p7 : w5;
    A1.u[2] = h1 ? w6 : p4;  A1.u[3] = h1 ? w7 : p5;

#pragma unroll
    for (int t = 0; t < 2; ++t) {
        const half8 vb0 = *(const half8*)(vsm + ql * VSTR        + koff + t * 32 + hi * 16);
        const half8 vb1 = *(const half8*)(vsm + (32 + ql) * VSTR + koff + t * 32 + hi * 16);
        const half8 pa = (t == 0) ? A0.h : A1.h;
        o0 = __builtin_amdgcn_mfma_f32_32x32x16_f16(pa, vb0, o0, 0, 0, 0);
        o1 = __builtin_amdgcn_mfma_f32_32x32x16_f16(pa, vb1, o1, 0, 0, 0);
    }
}

// ---------------- kernel 1: per-segment flash partials ----------------
__global__ __launch_bounds__(256) void attn_partial(
    const float* __restrict__ Qp, const float* __restrict__ Kp,
    const float* __restrict__ Vp, const int* __restrict__ VL,
    float* __restrict__ Opart, float2* __restrict__ ml,
    float* __restrict__ Op, int nseg)
{
    // K tile: 64 keys x 64 d halves, rows 128B, XOR-swizzled (verified)
    __shared__ alignas(16) char Ksm[KB * DD * 2];
    // V tile transposed: 64 d rows x 64 keys halves, VSTR-byte rows
    __shared__ alignas(16) char Vsm[DD * VSTR];

    const int tid  = threadIdx.x;
    const int wv   = tid >> 6;
    const int lane = tid & 63;
    const int ql   = lane & 31;
    const int hi   = lane >> 5;

    // seg fastest-varying: spreads heavy-batch work across dispatch order
    const int s   = blockIdx.x & (nseg - 1);
    const int rem = blockIdx.x / nseg;
    const int b   = rem >> 4;
    const int qt  = rem & 15;
    const int qbase = qt * QBLK + wv * 32;

    const int vlen = VL[b];
    const int SEG  = NKEY / nseg;
    const int kstart = s * SEG;
    const int kend   = min(kstart + SEG, vlen);

    if (kstart >= vlen) {
        if (tid < QBLK)
            ml[(size_t)(b * nseg + s) * NQ + qt * QBLK + tid] = make_float2(-1e30f, 0.f);
        return;
    }

    // ---- Q B-fragments: lane holds Q[qbase+ql][d = c*16 + hi*8 + j] ----
    const float* qsrc = Qp + ((size_t)b * NQ + qbase + ql) * DD;
    half8 qf[4];
#pragma unroll
    for (int c = 0; c < 4; ++c) {
        f32x4 f0 = *(const f32x4*)(qsrc + c * 16 + hi * 8);
        f32x4 f1 = *(const f32x4*)(qsrc + c * 16 + hi * 8 + 4);
        half8 h;
#pragma unroll
        for (int j = 0; j < 4; ++j) {
            h[j]     = (_Float16)(f0[j] * QSCALE);
            h[4 + j] = (_Float16)(f1[j] * QSCALE);
        }
        qf[c] = h;
    }

    f32x16 o0 = {}, o1 = {};
    float mrun = -1e30f, lrun = 0.f;

    const int skey = tid >> 3;          // 0..31
    const int sd0  = (tid & 7) * 8;     // 0..56
    const int vkey = tid & 31;          // 0..31
    const int vd0  = (tid >> 5) * 8;    // 0..56

    const int numt = (kend - kstart + KB - 1) / KB;

    for (int it = 0; it < numt; ++it) {
        const int kbase = kstart + it * KB;
        __syncthreads();

        // ---- stage K tile (64 rows, f32 -> f16), swizzled, coalesced ----
#pragma unroll
        for (int u = 0; u < 2; ++u) {
            const int row = skey + u * 32;
            const float* src = Kp + ((size_t)b * NKEY + kbase + row) * DD + sd0;
            f32x4 f0 = *(const f32x4*)src;
            f32x4 f1 = *(const f32x4*)(src + 4);
            half8 h;
#pragma unroll
            for (int j = 0; j < 4; ++j) {
                h[j]     = (_Float16)f0[j];
                h[4 + j] = (_Float16)f1[j];
            }
            const int off = (row * 128 + sd0 * 2) ^ ((row & 7) << 4);
            *(half8*)(Ksm + off) = h;
        }
        // ---- stage V tile transposed (64 keys), coalesced reads ----
#pragma unroll
        for (int u = 0; u < 2; ++u) {
            const int key = vkey + u * 32;
            const float* src = Vp + ((size_t)b * NKEY + kbase + key) * DD + vd0;
            f32x4 f0 = *(const f32x4*)src;
            f32x4 f1 = *(const f32x4*)(src + 4);
#pragma unroll
            for (int j = 0; j < 8; ++j) {
                const float x = (j < 4) ? f0[j] : f1[j - 4];
                *(_Float16*)(Vsm + (vd0 + j) * VSTR + key * 2) = (_Float16)x;
            }
        }
        __syncthreads();

        // ---- swapped QK^T, two independent 32-key chunks (from LDS) ----
        f32x16 svA = {}, svB = {};
#pragma unroll
        for (int c = 0; c < 4; ++c) {
            const half8 kfA = *(const half8*)(Ksm +
                ((ql * 128 + c * 32 + hi * 16) ^ ((ql & 7) << 4)));
            svA = __builtin_amdgcn_mfma_f32_32x32x16_f16(kfA, qf[c], svA, 0, 0, 0);
            const half8 kfB = *(const half8*)(Ksm +
                (((32 + ql) * 128 + c * 32 + hi * 16) ^ ((ql & 7) << 4)));
            svB = __builtin_amdgcn_mfma_f32_32x32x16_f16(kfB, qf[c], svB, 0, 0, 0);
        }

        // ---- mask (boundary iteration only; block-uniform branch) ----
        if (kbase + KB > vlen) {
#pragma unroll
            for (int r = 0; r < 16; ++r) {
                const int krow = (r & 3) + 8 * (r >> 2) + 4 * hi;
                svA[r] = (kbase + krow < vlen)      ? svA[r] : -1e30f;
                svB[r] = (kbase + 32 + krow < vlen) ? svB[r] : -1e30f;
            }
        }

        // ---- online softmax in log2 domain (lane state is q = ql) ----
        float mx[16];
#pragma unroll
        for (int r = 0; r < 16; ++r) mx[r] = fmaxf(svA[r], svB[r]);
#pragma unroll
        for (int st = 8; st > 0; st >>= 1)
#pragma unroll
            for (int r = 0; r < st; ++r) mx[r] = fmaxf(mx[r], mx[r + st]);
        float mr = fmaxf(mx[0], __shfl_xor(mx[0], 32));

        // defer-max: skip rescale if max grew <= 8 (P bounded by 2^8)
        if (!__all(mr <= mrun + 8.f)) {
            const float mn = fmaxf(mrun, mr);
            const float alpha = __builtin_amdgcn_exp2f(mrun - mn);
            lrun *= alpha;
            mrun = mn;
#pragma unroll
            for (int r = 0; r < 16; ++r) {
                const int qr = (r & 3) + 8 * (r >> 2) + 4 * hi;
                const float ar = __shfl(alpha, qr);
                o0[r] *= ar;
                o1[r] *= ar;
            }
        }

#pragma unroll
        for (int r = 0; r < 16; ++r) {
            svA[r] = __builtin_amdgcn_exp2f(svA[r] - mrun);
            svB[r] = __builtin_amdgcn_exp2f(svB[r] - mrun);
        }
        float sx[16];
#pragma unroll
        for (int r = 0; r < 16; ++r) sx[r] = svA[r] + svB[r];
#pragma unroll
        for (int st = 8; st > 0; st >>= 1)
#pragma unroll
            for (int r = 0; r < st; ++r) sx[r] += sx[r + st];
        lrun += sx[0] + __shfl_xor(sx[0], 32);

        // ---- PV for both chunks (V from LDS) ----
        pv_chunk(svA, Vsm, 0,  hi, ql, o0, o1);
        pv_chunk(svB, Vsm, 64, hi, ql, o0, o1);
    }

    // ---- epilogue: O rows q=(r&3)+8*(r>>2)+4*hi, cols d=ql+32u ----
    if (nseg == 1) {
#pragma unroll
        for (int r = 0; r < 16; ++r) {
            const int qr = (r & 3) + 8 * (r >> 2) + 4 * hi;
            const float inv = 1.0f / __shfl(lrun, qr);
            float* dst = Op + ((size_t)b * NQ + qbase + qr) * DD + ql;
            dst[0]  = o0[r] * inv;
            dst[32] = o1[r] * inv;
        }
    } else {
        float* dst0 = Opart + ((size_t)(b * nseg + s) * NQ + qbase) * DD;
#pragma unroll
        for (int r = 0; r < 16; ++r) {
            const int qr = (r & 3) + 8 * (r >> 2) + 4 * hi;
            float* dst = dst0 + (size_t)qr * DD + ql;
            dst[0]  = o0[r];
            dst[32] = o1[r];
        }
        if (hi == 0)
            ml[(size_t)(b * nseg + s) * NQ + qbase + ql] = make_float2(mrun, lrun);
    }
}

// ---------------- kernel 2: merge segment partials (log2-domain m) ----------------
__global__ __launch_bounds__(256) void attn_merge(
    const float* __restrict__ Opart, const float2* __restrict__ ml,
    float* __restrict__ Op, int nseg)
{
    const int lane = threadIdx.x & 63;
    const int row  = blockIdx.x * 4 + (threadIdx.x >> 6);
    const int b = row >> 11;
    const int q = row & (NQ - 1);

    float2 myml = make_float2(-1e30f, 0.f);
    if (lane < nseg)
        myml = ml[(size_t)(b * nseg + lane) * NQ + q];

    float M = -1e30f;
    for (int ss = 0; ss < nseg; ++ss)
        M = fmaxf(M, __shfl(myml.x, ss));

    float L = 0.f, acc = 0.f;
    for (int ss = 0; ss < nseg; ++ss) {
        const float ms = __shfl(myml.x, ss);
        const float ls = __shfl(myml.y, ss);
        if (ls > 0.f) {
            const float w = __builtin_amdgcn_exp2f(ms - M);
            L += w * ls;
            acc += w * Opart[((size_t)(b * nseg + ss) * NQ + q) * DD + lane];
        }
    }
    Op[((size_t)b * NQ + q) * DD + lane] = acc / L;
}

extern "C" void kernel_launch(void* const* d_in, const int* in_sizes, int n_in,
                              void* d_out, int out_size, void* d_ws, size_t ws_size,
                              hipStream_t stream) {
    const float* Qp = (const float*)d_in[0];
    const float* Kp = (const float*)d_in[1];
    const float* Vp = (const float*)d_in[2];
    const int*   VL = (const int*)d_in[3];
    float* Op = (float*)d_out;

    int nseg = 16;
    while (nseg > 1) {
        size_t need = (size_t)NB * nseg * NQ * DD * 4
                    + (size_t)NB * nseg * NQ * 8;
        if (ws_size >= need) break;
        nseg >>= 1;
    }

    float*  Opart = (float*)d_ws;
    float2* ml    = (float2*)((char*)d_ws + (size_t)NB * nseg * NQ * DD * 4);

    dim3 block(256);
    dim3 grid1(nseg * NB * (NQ / QBLK));
    hipLaunchKernelGGL(attn_partial, grid1, block, 0, stream,
                       Qp, Kp, Vp, VL, Opart, ml, Op, nseg);

    if (nseg > 1) {
        dim3 grid2(NB * NQ / 4);
        hipLaunchKernelGGL(attn_merge, grid2, block, 0, stream,
                           Opart, ml, Op, nseg);
    }
}

// Round 9
// 30.288 us; speedup vs baseline: 1.7864x; 1.7864x over previous
//
#include <hip/hip_runtime.h>

typedef float    f32x4  __attribute__((ext_vector_type(4)));
typedef float    f32x16 __attribute__((ext_vector_type(16)));
typedef _Float16 half8  __attribute__((ext_vector_type(8)));

constexpr int NB = 8;
constexpr int NQ = 2048;
constexpr int NKEY = 2048;
constexpr int DD = 64;
constexpr int KB = 64;   // keys per wave-iteration (two 32-key chunks)

// scores kept in log2 domain: fold log2(e) into the 1/sqrt(d) scale
#define QSCALE (0.125f * 1.44269504088896340736f)

__device__ inline unsigned pkh(float a, float b) {
    return __builtin_bit_cast(unsigned, __builtin_amdgcn_cvt_pkrtz(a, b));
}
// V^T LDS swizzle: byte(d,key) = d*128 + ((key*2) ^ vswz(d)); same fn on write+read
__device__ inline int vswz(int d) {
    return (((d >> 3) & 3) | ((d & 1) << 2)) << 4;
}

// P (f32 C-layout regs) -> f16 A-fragments (verified R5/R6), PV from swizzled V^T LDS.
__device__ __forceinline__ void pv_chunk(
    const f32x16& sv, const char* __restrict__ vsm, int koff,
    int hi, int ql, int swzq, f32x16& o0, f32x16& o1)
{
    const unsigned w0 = pkh(sv[0],  sv[1]),  w1 = pkh(sv[2],  sv[3]);
    const unsigned w2 = pkh(sv[4],  sv[5]),  w3 = pkh(sv[6],  sv[7]);
    const unsigned w4 = pkh(sv[8],  sv[9]),  w5 = pkh(sv[10], sv[11]);
    const unsigned w6 = pkh(sv[12], sv[13]), w7 = pkh(sv[14], sv[15]);
    const unsigned p0 = __shfl_xor(w0, 32), p1 = __shfl_xor(w1, 32);
    const unsigned p2 = __shfl_xor(w2, 32), p3 = __shfl_xor(w3, 32);
    const unsigned p4 = __shfl_xor(w4, 32), p5 = __shfl_xor(w5, 32);
    const unsigned p6 = __shfl_xor(w6, 32), p7 = __shfl_xor(w7, 32);
    const bool h1 = (hi != 0);
    union { unsigned u[4]; half8 h; } A0, A1;
    A0.u[0] = h1 ? p2 : w0;  A0.u[1] = h1 ? p3 : w1;
    A0.u[2] = h1 ? w2 : p0;  A0.u[3] = h1 ? w3 : p1;
    A1.u[0] = h1 ? p6 : w4;  A1.u[1] = h1 ? p7 : w5;
    A1.u[2] = h1 ? w6 : p4;  A1.u[3] = h1 ? w7 : p5;

#pragma unroll
    for (int t = 0; t < 2; ++t) {
        const int co = koff + t * 32 + hi * 16;       // key-byte offset in row
        const half8 vb0 = *(const half8*)(vsm + ql * 128        + (co ^ swzq));
        const half8 vb1 = *(const half8*)(vsm + (32 + ql) * 128 + (co ^ swzq));
        const half8 pa = (t == 0) ? A0.h : A1.h;
        o0 = __builtin_amdgcn_mfma_f32_32x32x16_f16(pa, vb0, o0, 0, 0, 0);
        o1 = __builtin_amdgcn_mfma_f32_32x32x16_f16(pa, vb1, o1, 0, 0, 0);
    }
}

// Fused flash attention: 1 block = 4 waves on one 32-q-row tile, split-K across
// waves, per-wave-private LDS staging (no main-loop barriers), LDS merge at end.
__global__ __launch_bounds__(256, 2) void attn_fused(
    const float* __restrict__ Qp, const float* __restrict__ Kp,
    const float* __restrict__ Vp, const int* __restrict__ VL,
    float* __restrict__ Op)
{
    // 4 x (K 8KB + V^T 8KB) staging; merge buffers overlaid after barrier
    __shared__ __align__(16) char pool[65536];

    const int tid  = threadIdx.x;
    const int wv   = tid >> 6;
    const int lane = tid & 63;
    const int ql   = lane & 31;
    const int hi   = lane >> 5;

    char* Ksm = pool + wv * 16384;
    char* Vsm = Ksm + 8192;

    // batch -> XCD pinning: XCD = blockIdx % 8 = b; batch K/V (2MB) stays L2-resident
    const int b  = blockIdx.x & 7;
    const int qt = blockIdx.x >> 3;      // 0..63
    const int qbase = qt * 32;

    const int vlen = VL[b];
    const int numt = (vlen + KB - 1) / KB;

    // ---- Q B-fragments: lane holds Q[qbase+ql][d = c*16 + hi*8 + j] ----
    const float* qsrc = Qp + ((size_t)b * NQ + qbase + ql) * DD;
    half8 qf[4];
#pragma unroll
    for (int c = 0; c < 4; ++c) {
        f32x4 f0 = *(const f32x4*)(qsrc + c * 16 + hi * 8);
        f32x4 f1 = *(const f32x4*)(qsrc + c * 16 + hi * 8 + 4);
        half8 h;
#pragma unroll
        for (int j = 0; j < 4; ++j) {
            h[j]     = (_Float16)(f0[j] * QSCALE);
            h[4 + j] = (_Float16)(f1[j] * QSCALE);
        }
        qf[c] = h;
    }

    f32x16 o0 = {}, o1 = {};
    float mrun = -1e30f, lrun = 0.f;

    // staging lane roles (all coalesced)
    const int kr_ = lane >> 3;          // K: row-in-8
    const int kd0 = (lane & 7) * 8;     // K: d0 (32B per lane)
    const int vk2 = (lane >> 4) * 2;    // V: key-pair base
    const int vd0 = (lane & 15) * 4;    // V: d0 (16B per lane)
    const int swzq = vswz(ql);          // == vswz(32+ql)

    // ---- main loop: wave wv owns key tiles wv, wv+4, ... (no barriers) ----
    for (int t = wv; t < numt; t += 4) {
        const int kbase = t * KB;
        const float* kbp = Kp + ((size_t)b * NKEY + kbase) * DD;
        const float* vbp = Vp + ((size_t)b * NKEY + kbase) * DD;

        // K tile loads (8 rows/instr, contiguous 256B rows)
        f32x4 ka[8][2];
#pragma unroll
        for (int i = 0; i < 8; ++i) {
            const float* src = kbp + (size_t)(i * 8 + kr_) * DD + kd0;
            ka[i][0] = *(const f32x4*)src;
            ka[i][1] = *(const f32x4*)(src + 4);
        }
        // V tile loads (key pairs, 16 lanes cover one 256B row)
        f32x4 va[8][2];
#pragma unroll
        for (int i = 0; i < 8; ++i) {
            const float* src = vbp + (size_t)(i * 8 + vk2) * DD + vd0;
            va[i][0] = *(const f32x4*)src;
            va[i][1] = *(const f32x4*)(src + DD);
        }

        // K -> LDS (f16, XOR-swizzled rows, b128 writes; R6-verified layout)
#pragma unroll
        for (int i = 0; i < 8; ++i) {
            half8 h;
#pragma unroll
            for (int j = 0; j < 4; ++j) {
                h[j]     = (_Float16)ka[i][0][j];
                h[4 + j] = (_Float16)ka[i][1][j];
            }
            const int off = ((i * 8 + kr_) * 128 + kd0 * 2) ^ (kr_ << 4);
            *(half8*)(Ksm + off) = h;
        }

        // ---- swapped QK^T, two 32-key chunks (K from LDS; R6 verified) ----
        f32x16 svA = {}, svB = {};
#pragma unroll
        for (int c = 0; c < 4; ++c) {
            const half8 kfA = *(const half8*)(Ksm +
                ((ql * 128 + c * 32 + hi * 16) ^ ((ql & 7) << 4)));
            svA = __builtin_amdgcn_mfma_f32_32x32x16_f16(kfA, qf[c], svA, 0, 0, 0);
            const half8 kfB = *(const half8*)(Ksm +
                (((32 + ql) * 128 + c * 32 + hi * 16) ^ ((ql & 7) << 4)));
            svB = __builtin_amdgcn_mfma_f32_32x32x16_f16(kfB, qf[c], svB, 0, 0, 0);
        }

        // V -> LDS transposed (key-pair packed b32 writes, swizzled)
#pragma unroll
        for (int i = 0; i < 8; ++i) {
#pragma unroll
            for (int jj = 0; jj < 4; ++jj) {
                const int d = vd0 + jj;
                const unsigned w = pkh(va[i][0][jj], va[i][1][jj]);
                *(unsigned*)(Vsm + d * 128 + (((i * 16 + vk2 * 2)) ^ vswz(d))) = w;
            }
        }

        // ---- mask (boundary tile only; wave-uniform branch) ----
        if (kbase + KB > vlen) {
#pragma unroll
            for (int r = 0; r < 16; ++r) {
                const int krow = (r & 3) + 8 * (r >> 2) + 4 * hi;
                svA[r] = (kbase + krow < vlen)      ? svA[r] : -1e30f;
                svB[r] = (kbase + 32 + krow < vlen) ? svB[r] : -1e30f;
            }
        }

        // ---- online softmax in log2 domain (lane state is q = ql) ----
        float mx[16];
#pragma unroll
        for (int r = 0; r < 16; ++r) mx[r] = fmaxf(svA[r], svB[r]);
#pragma unroll
        for (int st = 8; st > 0; st >>= 1)
#pragma unroll
            for (int r = 0; r < st; ++r) mx[r] = fmaxf(mx[r], mx[r + st]);
        float mr = fmaxf(mx[0], __shfl_xor(mx[0], 32));

        if (!__all(mr <= mrun + 8.f)) {     // defer-max (T13)
            const float mn = fmaxf(mrun, mr);
            const float alpha = __builtin_amdgcn_exp2f(mrun - mn);
            lrun *= alpha;
            mrun = mn;
#pragma unroll
            for (int r = 0; r < 16; ++r) {
                const int qr = (r & 3) + 8 * (r >> 2) + 4 * hi;
                const float ar = __shfl(alpha, qr);
                o0[r] *= ar;
                o1[r] *= ar;
            }
        }

#pragma unroll
        for (int r = 0; r < 16; ++r) {
            svA[r] = __builtin_amdgcn_exp2f(svA[r] - mrun);
            svB[r] = __builtin_amdgcn_exp2f(svB[r] - mrun);
        }
        float sx[16];
#pragma unroll
        for (int r = 0; r < 16; ++r) sx[r] = svA[r] + svB[r];
#pragma unroll
        for (int st = 8; st > 0; st >>= 1)
#pragma unroll
            for (int r = 0; r < st; ++r) sx[r] += sx[r + st];
        lrun += sx[0] + __shfl_xor(sx[0], 32);

        // ---- PV for both chunks (V^T from LDS) ----
        pv_chunk(svA, Vsm, 0,  hi, ql, swzq, o0, o1);
        pv_chunk(svB, Vsm, 64, hi, ql, swzq, o0, o1);
    }

    // ---- cross-wave merge (LDS overlaid on staging after barrier) ----
    __syncthreads();
    float* Mb = (float*)(pool + 32768);
    float* Lb = (float*)(pool + 32768 + 512);
    float* Tb = (float*)(pool + 32768 + 1024);
    float (*Obuf)[32][64] = (float (*)[32][64])pool;

    if (hi == 0) { Mb[wv * 32 + ql] = mrun; Lb[wv * 32 + ql] = lrun; }
    __syncthreads();

    float Mtot = -1e30f;
#pragma unroll
    for (int w = 0; w < 4; ++w)
        if (Lb[w * 32 + ql] > 0.f) Mtot = fmaxf(Mtot, Mb[w * 32 + ql]);
    float Ltot = 0.f;
#pragma unroll
    for (int w = 0; w < 4; ++w) {
        const float lw = Lb[w * 32 + ql];
        if (lw > 0.f) Ltot += lw * __builtin_amdgcn_exp2f(Mb[w * 32 + ql] - Mtot);
    }
    const float wown = (lrun > 0.f) ? __builtin_amdgcn_exp2f(mrun - Mtot) : 0.f;
    if (wv == 0 && hi == 0) Tb[ql] = Ltot;

#pragma unroll
    for (int r = 0; r < 16; ++r) {
        const int qr = (r & 3) + 8 * (r >> 2) + 4 * hi;
        const float wr = __shfl(wown, qr);
        Obuf[wv][qr][ql]      = o0[r] * wr;
        Obuf[wv][qr][ql + 32] = o1[r] * wr;
    }
    __syncthreads();

    // readback: wave wv sums q rows wv*8..+7; lane = d (coalesced 256B rows)
#pragma unroll
    for (int k = 0; k < 8; ++k) {
        const int q = wv * 8 + k;
        const float sum = Obuf[0][q][lane] + Obuf[1][q][lane]
                        + Obuf[2][q][lane] + Obuf[3][q][lane];
        Op[((size_t)b * NQ + qbase + q) * DD + lane] = sum / Tb[q];
    }
}

extern "C" void kernel_launch(void* const* d_in, const int* in_sizes, int n_in,
                              void* d_out, int out_size, void* d_ws, size_t ws_size,
                              hipStream_t stream) {
    const float* Qp = (const float*)d_in[0];
    const float* Kp = (const float*)d_in[1];
    const float* Vp = (const float*)d_in[2];
    const int*   VL = (const int*)d_in[3];
    float* Op = (float*)d_out;

    dim3 block(256);
    dim3 grid(NB * (NQ / 32));   // 512 blocks = 2/CU, fully resident
    hipLaunchKernelGGL(attn_fused, grid, block, 0, stream, Qp, Kp, Vp, VL, Op);
}